// Round 21
// baseline (203.178 us; speedup 1.0000x reference)
//
#include <hip/hip_runtime.h>

// VQ-VAE vector quantizer, MI355X — v18: code-split for 4 waves/SIMD.
// Grid 1024 = 512 token-tiles(128) x 2 code-halves; 256-thr/4-wave blocks;
// wave = 32 tokens x 256 codes (8 chunks x 32 codes, 18KB LDS) -> 4 blocks/CU,
// 16 waves/CU, desynced independent blocks overlap ds_read/MFMA/VALU/stage.
// Cross-half merge: u64 atomicMax win-array; SECOND finisher block per tile
// (device atomicAdd flag) gathers winners and writes the output (no scatter
// kernel). win/flags zeroed by prep each call.
// score(t,k) = x_t . e_k - 0.5*||e_k||^2  (argmax == argmin distance)
// x.e = xh.eh + (xh.el' + xl'.eh)/2048, *_lo' = (v - fp16(v))*2048 as fp16.

typedef _Float16 f16;
typedef _Float16 f16x4 __attribute__((ext_vector_type(4)));
typedef _Float16 f16x8 __attribute__((ext_vector_type(8)));
typedef float f32x16 __attribute__((ext_vector_type(16)));

#define ND 128
#define NK 512
#define NHW 4096
#define LO_SCALE 2048.0f
#define LO_INV (1.0f / 2048.0f)

// workspace layout (bytes)
#define WS_EHI 0
#define WS_ELO 131072u
#define WS_ENS 262144u
#define WS_WIN 264192u      // 65536 x u64 = 512KB
#define WS_FLG 788480u      // 512 x int
#define WS_NEED 790528u

__device__ __forceinline__ unsigned mono_key(float v) {
  const unsigned u = __float_as_uint(v);
  return (u & 0x80000000u) ? ~u : (u | 0x80000000u);
}

// ================================================================ prep ======
// blocks 0..31: split e SWIZZLED (16B slot ^= code&15) + 0.5*||e||^2
// blocks 32..287: zero win; block 288: zero flags.
__global__ __launch_bounds__(256) void vq_prep_e(const float* __restrict__ e,
                                                 f16* __restrict__ ehi, f16* __restrict__ elo,
                                                 float* __restrict__ ens,
                                                 unsigned long long* __restrict__ win,
                                                 int* __restrict__ flg) {
  const int tid = threadIdx.x;
  if (blockIdx.x >= 288) {
    flg[tid] = 0; flg[tid + 256] = 0;
    return;
  }
  if (blockIdx.x >= 32) {
    win[((int)blockIdx.x - 32) * 256 + tid] = 0ull;
    return;
  }
  const int k0 = (int)blockIdx.x * 16;
  const int r = tid >> 4, dq16 = tid & 15;
  const int k = k0 + r;
  float ssum = 0.0f;
  #pragma unroll
  for (int hh = 0; hh < 2; ++hh) {
    const int dq = dq16 + 16 * hh;
    const float4 v = *(const float4*)(e + (size_t)k * ND + 4 * dq);
    ssum += v.x * v.x + v.y * v.y + v.z * v.z + v.w * v.w;
    float va[4] = {v.x, v.y, v.z, v.w};
    f16x4 hv, lv;
    #pragma unroll
    for (int j = 0; j < 4; ++j) {
      const f16 h = (f16)va[j];
      hv[j] = h;
      lv[j] = (f16)((va[j] - (float)h) * LO_SCALE);
    }
    const int sl = (dq >> 1) ^ (k & 15);            // 16B-slot swizzle
    const size_t off = (size_t)k * ND + sl * 8 + (dq & 1) * 4;
    *(f16x4*)(ehi + off) = hv;
    *(f16x4*)(elo + off) = lv;
  }
  #pragma unroll
  for (int m = 1; m < 16; m <<= 1) ssum += __shfl_xor(ssum, m, 64);
  if (dq16 == 0) ens[k] = 0.5f * ssum;
}

// =============================================================== score ======
__global__ __launch_bounds__(256) void vq_score(const float* __restrict__ x,
                                                const f16* __restrict__ ehi,
                                                const f16* __restrict__ elo,
                                                const float* __restrict__ ens,
                                                const float* __restrict__ e32,
                                                unsigned long long* __restrict__ win,
                                                int* __restrict__ flg,
                                                float* __restrict__ out) {
  __shared__ f16 eh_s[32 * 128];      // 8KB [code*128 + swz slot]
  __shared__ f16 el_s[32 * 128];      // 8KB
  __shared__ float ens_s[256];        // 1KB (this half's biases)
  __shared__ unsigned long long cand[128];
  __shared__ int bidx_s[128];
  __shared__ int amSecond;

  const int tid = threadIdx.x;        // 0..255
  const int w = tid >> 6;             // wave 0..3
  const int lane = tid & 63;
  const int l31 = lane & 31;
  const int half = lane >> 5;
  const int tile = (int)blockIdx.x >> 1;
  const int bc = (int)blockIdx.x & 1; // code half 0/1
  const int T0 = tile * 128;
  const int tok = T0 + w * 32 + l31;  // this lane's token
  const int bb = tok >> 12;           // tile never crosses batch
  const int hw = tok & 4095;
  const int sbase = l31 & 15;         // swizzle key (== code&15 for row l31)
  const f16* ghb = ehi + (size_t)bc * 32768;
  const f16* glb = elo + (size_t)bc * 32768;

  ens_s[tid] = ens[bc * 256 + tid];

  // x: direct strided-coalesced NCHW loads + in-register fp16 split,
  // already in fragment order (d-octet = 2ks+half)
  f16x8 Bh[8], Bl[8];
  {
    const float* xb = x + (size_t)bb * ND * NHW + hw;
    #pragma unroll
    for (int ks = 0; ks < 8; ++ks) {
      const int oct = 2 * ks + half;
      #pragma unroll
      for (int j = 0; j < 8; ++j) {
        const float v = xb[(size_t)(oct * 8 + j) * NHW];
        const f16 hv = (f16)v;
        Bh[ks][j] = hv;
        Bl[ks][j] = (f16)((v - (float)hv) * LO_SCALE);
      }
    }
  }

  float bv = -3.0e38f;
  int bi = 0;                         // code LOCAL to this half

  for (int c = 0; c < 8; ++c) {
    // stage chunk c: 32 codes x 128 f16 hi+lo (256 thr x 16B x 2 ops each)
    {
      const f16* gh = ghb + c * 4096;
      const f16* gl = glb + c * 4096;
      #pragma unroll
      for (int p = 0; p < 2; ++p) {
        __builtin_amdgcn_global_load_lds(gh + p * 2048 + tid * 8, &eh_s[p * 2048 + tid * 8], 16, 0, 0);
        __builtin_amdgcn_global_load_lds(gl + p * 2048 + tid * 8, &el_s[p * 2048 + tid * 8], 16, 0, 0);
      }
    }
    __syncthreads();                  // staged (vmcnt drained by barrier)

    const f16* ah = &eh_s[l31 * 128]; // lane's code row in chunk (A operand)
    const f16* al = &el_s[l31 * 128];
    f32x16 a1 = {}, a2 = {};
    __builtin_amdgcn_s_setprio(1);
    #pragma unroll
    for (int ks = 0; ks < 8; ++ks) {
      const int sl = ((2 * ks + half) ^ sbase) * 8;
      const f16x8 Ah = *(const f16x8*)(ah + sl);
      const f16x8 Al = *(const f16x8*)(al + sl);
      a2 = __builtin_amdgcn_mfma_f32_32x32x16_f16(Al, Bh[ks], a2, 0, 0, 0);
      a1 = __builtin_amdgcn_mfma_f32_32x32x16_f16(Ah, Bh[ks], a1, 0, 0, 0);
      a2 = __builtin_amdgcn_mfma_f32_32x32x16_f16(Ah, Bl[ks], a2, 0, 0, 0);
    }
    __builtin_amdgcn_s_setprio(0);

    // bias rows for this lane: rowr = (rr&3) + 8*(rr>>2) + 4*half
    const int kb = c * 32 + 4 * half;
    const float4 b0 = *(const float4*)&ens_s[kb + 0];
    const float4 b1 = *(const float4*)&ens_s[kb + 8];
    const float4 b2 = *(const float4*)&ens_s[kb + 16];
    const float4 b3 = *(const float4*)&ens_s[kb + 24];
    const float bias[16] = {b0.x, b0.y, b0.z, b0.w, b1.x, b1.y, b1.z, b1.w,
                            b2.x, b2.y, b2.z, b2.w, b3.x, b3.y, b3.z, b3.w};
    #pragma unroll
    for (int rr = 0; rr < 16; ++rr) {
      const float s = a1[rr] + a2[rr] * LO_INV - bias[rr];
      const int code = kb + (rr & 3) + 8 * (rr >> 2);
      if (s > bv) { bv = s; bi = code; }  // ascending local code: > keeps lowest
    }
    __syncthreads();                  // all reads done before restage
  }

  // merge across lane-halves (same token for lane ^ 32)
  {
    const float ov = __shfl_xor(bv, 32, 64);
    const int oi = __shfl_xor(bi, 32, 64);
    if (ov > bv || (ov == bv && oi < bi)) { bv = ov; bi = oi; }
  }
  // global key: ties -> lower global code via 511-gcode
  {
    const int gcode = bc * 256 + bi;
    const unsigned long long key =
        ((unsigned long long)mono_key(bv) << 32) | (unsigned)(511 - gcode);
    if (half == 0) cand[w * 32 + l31] = key;
  }
  __syncthreads();
  if (tid < 128) atomicMax(win + T0 + tid, cand[tid]);
  __syncthreads();                    // barrier waits vmcnt(0): atomics visible
  __threadfence();
  if (tid == 0) amSecond = (atomicAdd(flg + tile, 1) == 1);
  __syncthreads();
  if (!amSecond) return;              // the other half-block will write

  // finisher: gather winners (coherent atomic reads) and write output
  __threadfence();
  if (tid < 128) {
    const unsigned long long k = atomicMax(win + T0 + tid, 0ull);
    bidx_s[tid] = 511 - (int)(k & 0x1FFull);
  }
  __syncthreads();
  {
    const int tl = tid & 127, dg = tid >> 7;      // token, d-half (0/1)
    const int Tg = T0 + tl;
    const int ohw = Tg & 4095;
    const float* er = e32 + (size_t)bidx_s[tl] * ND + dg * 64;
    float* ob = out + (size_t)bb * ND * NHW + (size_t)(dg * 64) * NHW + ohw;
    #pragma unroll
    for (int j4 = 0; j4 < 16; ++j4) {
      const float4 ev = *(const float4*)(er + j4 * 4);
      ob[(size_t)(j4 * 4 + 0) * NHW] = ev.x;
      ob[(size_t)(j4 * 4 + 1) * NHW] = ev.y;
      ob[(size_t)(j4 * 4 + 2) * NHW] = ev.z;
      ob[(size_t)(j4 * 4 + 3) * NHW] = ev.w;
    }
  }
}

// ======================================================== fp32 fallback =====
__global__ __launch_bounds__(128) void vq_enorm(const float* __restrict__ e,
                                                float* __restrict__ ensw) {
  const int k = blockIdx.x;
  const int d = threadIdx.x;
  const float v = e[k * ND + d];
  float s = v * v;
  #pragma unroll
  for (int off = 32; off > 0; off >>= 1) s += __shfl_down(s, off, 64);
  __shared__ float tmp[2];
  if ((d & 63) == 0) tmp[d >> 6] = s;
  __syncthreads();
  if (d == 0) ensw[k] = tmp[0] + tmp[1];
}

__global__ __launch_bounds__(256, 2) void vq_main_f32(const float* __restrict__ x,
                                                      const float* __restrict__ e,
                                                      const float* __restrict__ ensw,
                                                      float* __restrict__ out) {
  __shared__ float xs[ND][64];
  __shared__ float esh[ND][64];
  __shared__ float enh[NK];
  __shared__ float red_v[64][17];
  __shared__ int red_i[64][17];
  __shared__ int bidx[64];
  const int tid = threadIdx.x;
  const int b = blockIdx.x >> 6;
  const int hw0 = (blockIdx.x & 63) * 64;
  const float* xb = x + ((size_t)b * ND) * NHW;
  #pragma unroll
  for (int i = 0; i < 8; ++i) {
    const int f = tid + 256 * i;
    const int d = f >> 4, t4 = f & 15;
    const float4 v = *(const float4*)(xb + (size_t)d * NHW + hw0 + 4 * t4);
    *(float4*)&xs[d][4 * t4] = v;
  }
  #pragma unroll
  for (int i = 0; i < 2; ++i) enh[tid + 256 * i] = ensw[tid + 256 * i];
  const int t4 = tid & 15, m = tid >> 4;
  float bvv[4] = {-3.0e38f, -3.0e38f, -3.0e38f, -3.0e38f};
  int bii[4] = {0, 0, 0, 0};
  for (int kc = 0; kc < NK / 64; ++kc) {
    __syncthreads();
    #pragma unroll
    for (int i = 0; i < 8; ++i) {
      const int f = tid + 256 * i;
      const int kk = f & 63, dq = f >> 6;
      const float4 v = *(const float4*)(e + (size_t)(kc * 64 + kk) * ND + 4 * dq);
      esh[4 * dq + 0][kk] = v.x; esh[4 * dq + 1][kk] = v.y;
      esh[4 * dq + 2][kk] = v.z; esh[4 * dq + 3][kk] = v.w;
    }
    __syncthreads();
    float acc[4][4];
    #pragma unroll
    for (int a = 0; a < 4; ++a)
      #pragma unroll
      for (int cc = 0; cc < 4; ++cc) acc[a][cc] = 0.0f;
    #pragma unroll 8
    for (int d = 0; d < 128; ++d) {
      const float4 xv = *(const float4*)&xs[d][4 * t4];
      const float4 ev = *(const float4*)&esh[d][4 * m];
      const float xa[4] = {xv.x, xv.y, xv.z, xv.w};
      const float ea[4] = {ev.x, ev.y, ev.z, ev.w};
      #pragma unroll
      for (int a = 0; a < 4; ++a)
        #pragma unroll
        for (int cc = 0; cc < 4; ++cc) acc[a][cc] = fmaf(xa[a], ea[cc], acc[a][cc]);
    }
    const int kbase = kc * 64 + 4 * m;
    #pragma unroll
    for (int cc = 0; cc < 4; ++cc) {
      const float bias = 0.5f * enh[kbase + cc];
      const int kg = kbase + cc;
      #pragma unroll
      for (int a = 0; a < 4; ++a) {
        const float s = acc[a][cc] - bias;
        if (s > bvv[a] || (s == bvv[a] && kg < bii[a])) { bvv[a] = s; bii[a] = kg; }
      }
    }
  }
  #pragma unroll
  for (int a = 0; a < 4; ++a) { red_v[4 * t4 + a][m] = bvv[a]; red_i[4 * t4 + a][m] = bii[a]; }
  __syncthreads();
  if (tid < 64) {
    float v = red_v[tid][0]; int ix = red_i[tid][0];
    #pragma unroll
    for (int j = 1; j < 16; ++j) {
      const float vj = red_v[tid][j]; const int ij = red_i[tid][j];
      if (vj > v || (vj == v && ij < ix)) { v = vj; ix = ij; }
    }
    bidx[tid] = ix;
  }
  __syncthreads();
  const int t = tid & 63, dgg = tid >> 6;
  const float* er = e + (size_t)bidx[t] * ND;
  float* ob = out + ((size_t)b * ND) * NHW + hw0 + t;
  #pragma unroll
  for (int i = 0; i < 32; ++i) ob[(size_t)(dgg * 32 + i) * NHW] = er[dgg * 32 + i];
}

// --------------------------------------------------------------- launch -----
extern "C" void kernel_launch(void* const* d_in, const int* in_sizes, int n_in,
                              void* d_out, int out_size, void* d_ws, size_t ws_size,
                              hipStream_t stream) {
  const float* x = (const float*)d_in[0];
  const float* e = (const float*)d_in[1];
  float* out = (float*)d_out;
  char* ws = (char*)d_ws;

  if (ws_size >= WS_NEED) {
    f16* ehi = (f16*)(ws + WS_EHI);
    f16* elo = (f16*)(ws + WS_ELO);
    float* ens = (float*)(ws + WS_ENS);
    unsigned long long* win = (unsigned long long*)(ws + WS_WIN);
    int* flg = (int*)(ws + WS_FLG);
    vq_prep_e<<<289, 256, 0, stream>>>(e, ehi, elo, ens, win, flg);
    vq_score<<<1024, 256, 0, stream>>>(x, ehi, elo, ens, e, win, flg, out);
  } else {
    float* ensw = (float*)d_ws;
    vq_enorm<<<512, 128, 0, stream>>>(e, ensw);
    vq_main_f32<<<16 * 64, 256, 0, stream>>>(x, e, ensw, out);
  }
}

// Round 24
// 44.611 us; speedup vs baseline: 4.5545x; 4.5545x over previous
//
#include <hip/hip_runtime.h>

// VQ-VAE vector quantizer, MI355X — v16 (FINAL, best verified: 44.2 µs).
// Block = 128 tokens x ALL 512 codes, 256 thr / 4 waves, grid 512.
// Wave owns 32 tokens (B-frags in regs from direct NCHW read + in-reg fp16
// split); e streams through double-buffered LDS with counted s_waitcnt
// vmcnt(8) (never 0 in main loop) + raw s_barrier; fused direct output write.
// score(t,k) = x_t . e_k - 0.5*||e_k||^2  (argmax == argmin distance)
// x.e = xh.eh + (xh.el' + xl'.eh)/2048, *_lo' = (v - fp16(v))*2048 as fp16.

typedef _Float16 f16;
typedef _Float16 f16x4 __attribute__((ext_vector_type(4)));
typedef _Float16 f16x8 __attribute__((ext_vector_type(8)));
typedef float f32x16 __attribute__((ext_vector_type(16)));

#define ND 128
#define NK 512
#define NHW 4096
#define LO_SCALE 2048.0f
#define LO_INV (1.0f / 2048.0f)

// workspace layout (bytes): e-split only
#define WS_EHI 0
#define WS_ELO 131072u
#define WS_ENS 262144u
#define WS_NEED 264192u

// ================================================================ prep ======
// 32 blocks x 256 thr: split e SWIZZLED (16B slot ^= code&15) + 0.5*||e||^2
__global__ __launch_bounds__(256) void vq_prep_e(const float* __restrict__ e,
                                                 f16* __restrict__ ehi, f16* __restrict__ elo,
                                                 float* __restrict__ ens) {
  const int tid = threadIdx.x;
  const int k0 = (int)blockIdx.x * 16;
  const int r = tid >> 4, dq16 = tid & 15;
  const int k = k0 + r;
  float ssum = 0.0f;
  #pragma unroll
  for (int hh = 0; hh < 2; ++hh) {
    const int dq = dq16 + 16 * hh;
    const float4 v = *(const float4*)(e + (size_t)k * ND + 4 * dq);
    ssum += v.x * v.x + v.y * v.y + v.z * v.z + v.w * v.w;
    float va[4] = {v.x, v.y, v.z, v.w};
    f16x4 hv, lv;
    #pragma unroll
    for (int j = 0; j < 4; ++j) {
      const f16 h = (f16)va[j];
      hv[j] = h;
      lv[j] = (f16)((va[j] - (float)h) * LO_SCALE);
    }
    const int sl = (dq >> 1) ^ (k & 15);            // 16B-slot swizzle
    const size_t off = (size_t)k * ND + sl * 8 + (dq & 1) * 4;
    *(f16x4*)(ehi + off) = hv;
    *(f16x4*)(elo + off) = lv;
  }
  #pragma unroll
  for (int m = 1; m < 16; m <<= 1) ssum += __shfl_xor(ssum, m, 64);
  if (dq16 == 0) ens[k] = 0.5f * ssum;
}

// =============================================================== score ======
// grid 512 x 256 thr (4 waves). Double-buffered chunks with COUNTED vmcnt:
//   iter c: [buf(cur)=chunk c ready] compute(c) ; s_barrier (reads done) ;
//           stage(c+2 -> buf(cur)) ; s_waitcnt vmcnt(8)  (c+1 landed) ;
//           s_barrier ; swap.
__global__ __launch_bounds__(256) void vq_score(const float* __restrict__ x,
                                                const f16* __restrict__ ehi,
                                                const f16* __restrict__ elo,
                                                const float* __restrict__ ens,
                                                const float* __restrict__ e32,
                                                float* __restrict__ out) {
  __shared__ f16 eh_s[2][64 * 128];   // 2 x 16KB [buf][code*128 + swz slot]
  __shared__ f16 el_s[2][64 * 128];   // 2 x 16KB
  __shared__ float ens_s[NK];         // 2KB                      (total 66KB)

  const int tid = threadIdx.x;        // 0..255
  const int w = tid >> 6;             // wave 0..3
  const int lane = tid & 63;
  const int l31 = lane & 31;
  const int half = lane >> 5;
  const int T0 = (int)blockIdx.x * 128;
  const int tok = T0 + w * 32 + l31;  // this lane's token
  const int bb = tok >> 12;
  const int hw = tok & 4095;
  const int sbase = l31 & 15;         // swizzle key (== code&15 for row l31)

  // ens first: its ds_write forces a wait that drains only these 2 loads
  ens_s[tid] = ens[tid];
  ens_s[tid + 256] = ens[tid + 256];

  // x loads (oldest large batch) + in-register fp16 split, fragment order
  f16x8 Bh[8], Bl[8];
  {
    const float* xb = x + (size_t)bb * ND * NHW + hw;
    #pragma unroll
    for (int ks = 0; ks < 8; ++ks) {
      const int oct = 2 * ks + half;
      #pragma unroll
      for (int j = 0; j < 8; ++j) {
        const float v = xb[(size_t)(oct * 8 + j) * NHW];
        const f16 hv = (f16)v;
        Bh[ks][j] = hv;
        Bl[ks][j] = (f16)((v - (float)hv) * LO_SCALE);
      }
    }
  }

  // stage chunk 0 -> buf0, chunk 1 -> buf1 (8 gload_lds ops per chunk)
  #pragma unroll
  for (int p = 0; p < 4; ++p) {
    __builtin_amdgcn_global_load_lds(ehi + p * 2048 + tid * 8, &eh_s[0][p * 2048 + tid * 8], 16, 0, 0);
    __builtin_amdgcn_global_load_lds(elo + p * 2048 + tid * 8, &el_s[0][p * 2048 + tid * 8], 16, 0, 0);
  }
  #pragma unroll
  for (int p = 0; p < 4; ++p) {
    __builtin_amdgcn_global_load_lds(ehi + 8192 + p * 2048 + tid * 8, &eh_s[1][p * 2048 + tid * 8], 16, 0, 0);
    __builtin_amdgcn_global_load_lds(elo + 8192 + p * 2048 + tid * 8, &el_s[1][p * 2048 + tid * 8], 16, 0, 0);
  }

  // chunk0 landed (chunk1's 8 ops may remain in flight)
  asm volatile("s_waitcnt vmcnt(8)" ::: "memory");
  __builtin_amdgcn_sched_barrier(0);
  __builtin_amdgcn_s_barrier();

  float bv = -3.0e38f;
  int bi = 0;

  for (int c = 0; c < 8; ++c) {
    const int cur = c & 1;
    // ---- compute chunk c from buf[cur] ----
    #pragma unroll
    for (int cg = 0; cg < 2; ++cg) {
      const int r = cg * 32 + l31;              // lane's code row in chunk (A)
      const f16* ah = &eh_s[cur][r * 128];
      const f16* al = &el_s[cur][r * 128];
      f32x16 a1 = {}, a2 = {};
      __builtin_amdgcn_s_setprio(1);
      #pragma unroll
      for (int ks = 0; ks < 8; ++ks) {
        const int sl = ((2 * ks + half) ^ sbase) * 8;
        const f16x8 Ah = *(const f16x8*)(ah + sl);
        const f16x8 Al = *(const f16x8*)(al + sl);
        a2 = __builtin_amdgcn_mfma_f32_32x32x16_f16(Al, Bh[ks], a2, 0, 0, 0);
        a1 = __builtin_amdgcn_mfma_f32_32x32x16_f16(Ah, Bh[ks], a1, 0, 0, 0);
        a2 = __builtin_amdgcn_mfma_f32_32x32x16_f16(Ah, Bl[ks], a2, 0, 0, 0);
      }
      __builtin_amdgcn_s_setprio(0);
      // bias rows for this lane: rowr = (rr&3) + 8*(rr>>2) + 4*half
      const int kb = c * 64 + cg * 32 + 4 * half;
      const float4 b0 = *(const float4*)&ens_s[kb + 0];
      const float4 b1 = *(const float4*)&ens_s[kb + 8];
      const float4 b2 = *(const float4*)&ens_s[kb + 16];
      const float4 b3 = *(const float4*)&ens_s[kb + 24];
      const float bias[16] = {b0.x, b0.y, b0.z, b0.w, b1.x, b1.y, b1.z, b1.w,
                              b2.x, b2.y, b2.z, b2.w, b3.x, b3.y, b3.z, b3.w};
      #pragma unroll
      for (int rr = 0; rr < 16; ++rr) {
        const float s = a1[rr] + a2[rr] * LO_INV - bias[rr];
        const int code = kb + (rr & 3) + 8 * (rr >> 2);
        if (s > bv) { bv = s; bi = code; }  // ascending code: > keeps lowest
      }
    }
    // ---- pipeline boundary: reads of buf[cur] done -> restage it ----
    __builtin_amdgcn_s_barrier();           // all waves done reading buf[cur]
    if (c + 2 <= 7) {
      const f16* gh = ehi + (c + 2) * 8192;
      const f16* gl = elo + (c + 2) * 8192;
      f16* dh = &eh_s[cur][0];
      f16* dl = &el_s[cur][0];
      #pragma unroll
      for (int p = 0; p < 4; ++p) {
        __builtin_amdgcn_global_load_lds(gh + p * 2048 + tid * 8, dh + p * 2048 + tid * 8, 16, 0, 0);
        __builtin_amdgcn_global_load_lds(gl + p * 2048 + tid * 8, dl + p * 2048 + tid * 8, 16, 0, 0);
      }
      asm volatile("s_waitcnt vmcnt(8)" ::: "memory");   // chunk c+1 landed
    } else if (c == 6) {
      asm volatile("s_waitcnt vmcnt(0)" ::: "memory");   // chunk 7 landed
    }
    __builtin_amdgcn_sched_barrier(0);
    __builtin_amdgcn_s_barrier();           // buf[(c+1)&1] ready for all
  }

  // merge across lane-halves (same token for lane ^ 32)
  {
    const float ov = __shfl_xor(bv, 32, 64);
    const int oi = __shfl_xor(bi, 32, 64);
    if (ov > bv || (ov == bv && oi < bi)) { bv = ov; bi = oi; }
  }

  // fused output write: lane covers token `tok`, d-range half*64..+64
  {
    const float* er = e32 + (size_t)bi * ND + half * 64;
    float* ob = out + (size_t)bb * ND * NHW + (size_t)(half * 64) * NHW + hw;
    #pragma unroll
    for (int j4 = 0; j4 < 16; ++j4) {
      const float4 ev = *(const float4*)(er + j4 * 4);
      ob[(size_t)(j4 * 4 + 0) * NHW] = ev.x;
      ob[(size_t)(j4 * 4 + 1) * NHW] = ev.y;
      ob[(size_t)(j4 * 4 + 2) * NHW] = ev.z;
      ob[(size_t)(j4 * 4 + 3) * NHW] = ev.w;
    }
  }
}

// ======================================================== fp32 fallback =====
__global__ __launch_bounds__(128) void vq_enorm(const float* __restrict__ e,
                                                float* __restrict__ ensw) {
  const int k = blockIdx.x;
  const int d = threadIdx.x;
  const float v = e[k * ND + d];
  float s = v * v;
  #pragma unroll
  for (int off = 32; off > 0; off >>= 1) s += __shfl_down(s, off, 64);
  __shared__ float tmp[2];
  if ((d & 63) == 0) tmp[d >> 6] = s;
  __syncthreads();
  if (d == 0) ensw[k] = tmp[0] + tmp[1];
}

__global__ __launch_bounds__(256, 2) void vq_main_f32(const float* __restrict__ x,
                                                      const float* __restrict__ e,
                                                      const float* __restrict__ ensw,
                                                      float* __restrict__ out) {
  __shared__ float xs[ND][64];
  __shared__ float esh[ND][64];
  __shared__ float enh[NK];
  __shared__ float red_v[64][17];
  __shared__ int red_i[64][17];
  __shared__ int bidx[64];
  const int tid = threadIdx.x;
  const int b = blockIdx.x >> 6;
  const int hw0 = (blockIdx.x & 63) * 64;
  const float* xb = x + ((size_t)b * ND) * NHW;
  #pragma unroll
  for (int i = 0; i < 8; ++i) {
    const int f = tid + 256 * i;
    const int d = f >> 4, t4 = f & 15;
    const float4 v = *(const float4*)(xb + (size_t)d * NHW + hw0 + 4 * t4);
    *(float4*)&xs[d][4 * t4] = v;
  }
  #pragma unroll
  for (int i = 0; i < 2; ++i) enh[tid + 256 * i] = ensw[tid + 256 * i];
  const int t4 = tid & 15, m = tid >> 4;
  float bvv[4] = {-3.0e38f, -3.0e38f, -3.0e38f, -3.0e38f};
  int bii[4] = {0, 0, 0, 0};
  for (int kc = 0; kc < NK / 64; ++kc) {
    __syncthreads();
    #pragma unroll
    for (int i = 0; i < 8; ++i) {
      const int f = tid + 256 * i;
      const int kk = f & 63, dq = f >> 6;
      const float4 v = *(const float4*)(e + (size_t)(kc * 64 + kk) * ND + 4 * dq);
      esh[4 * dq + 0][kk] = v.x; esh[4 * dq + 1][kk] = v.y;
      esh[4 * dq + 2][kk] = v.z; esh[4 * dq + 3][kk] = v.w;
    }
    __syncthreads();
    float acc[4][4];
    #pragma unroll
    for (int a = 0; a < 4; ++a)
      #pragma unroll
      for (int cc = 0; cc < 4; ++cc) acc[a][cc] = 0.0f;
    #pragma unroll 8
    for (int d = 0; d < 128; ++d) {
      const float4 xv = *(const float4*)&xs[d][4 * t4];
      const float4 ev = *(const float4*)&esh[d][4 * m];
      const float xa[4] = {xv.x, xv.y, xv.z, xv.w};
      const float ea[4] = {ev.x, ev.y, ev.z, ev.w};
      #pragma unroll
      for (int a = 0; a < 4; ++a)
        #pragma unroll
        for (int cc = 0; cc < 4; ++cc) acc[a][cc] = fmaf(xa[a], ea[cc], acc[a][cc]);
    }
    const int kbase = kc * 64 + 4 * m;
    #pragma unroll
    for (int cc = 0; cc < 4; ++cc) {
      const float bias = 0.5f * enh[kbase + cc];
      const int kg = kbase + cc;
      #pragma unroll
      for (int a = 0; a < 4; ++a) {
        const float s = acc[a][cc] - bias;
        if (s > bvv[a] || (s == bvv[a] && kg < bii[a])) { bvv[a] = s; bii[a] = kg; }
      }
    }
  }
  #pragma unroll
  for (int a = 0; a < 4; ++a) { red_v[4 * t4 + a][m] = bvv[a]; red_i[4 * t4 + a][m] = bii[a]; }
  __syncthreads();
  if (tid < 64) {
    float v = red_v[tid][0]; int ix = red_i[tid][0];
    #pragma unroll
    for (int j = 1; j < 16; ++j) {
      const float vj = red_v[tid][j]; const int ij = red_i[tid][j];
      if (vj > v || (vj == v && ij < ix)) { v = vj; ix = ij; }
    }
    bidx[tid] = ix;
  }
  __syncthreads();
  const int t = tid & 63, dgg = tid >> 6;
  const float* er = e + (size_t)bidx[t] * ND;
  float* ob = out + ((size_t)b * ND) * NHW + hw0 + t;
  #pragma unroll
  for (int i = 0; i < 32; ++i) ob[(size_t)(dgg * 32 + i) * NHW] = er[dgg * 32 + i];
}

// --------------------------------------------------------------- launch -----
extern "C" void kernel_launch(void* const* d_in, const int* in_sizes, int n_in,
                              void* d_out, int out_size, void* d_ws, size_t ws_size,
                              hipStream_t stream) {
  const float* x = (const float*)d_in[0];
  const float* e = (const float*)d_in[1];
  float* out = (float*)d_out;
  char* ws = (char*)d_ws;

  if (ws_size >= WS_NEED) {
    f16* ehi = (f16*)(ws + WS_EHI);
    f16* elo = (f16*)(ws + WS_ELO);
    float* ens = (float*)(ws + WS_ENS);
    vq_prep_e<<<32, 256, 0, stream>>>(e, ehi, elo, ens);
    vq_score<<<512, 256, 0, stream>>>(x, ehi, elo, ens, e, out);
  } else {
    float* ensw = (float*)d_ws;
    vq_enorm<<<512, 128, 0, stream>>>(e, ensw);
    vq_main_f32<<<16 * 64, 256, 0, stream>>>(x, e, ensw, out);
  }
}